// Round 5
// baseline (6653.896 us; speedup 1.0000x reference)
//
#include <hip/hip_runtime.h>
#include <hip/hip_bf16.h>
#include <stdint.h>
#include <stddef.h>
#include <string.h>

#define NN 100000      // nodes
#define NE 256000      // edges
#define EMBD 300
#define C1D 600        // 2*EMB
#define NL 5
#define BNEPS 1e-5f

typedef short bf16x8 __attribute__((ext_vector_type(8)));
typedef float f32x4 __attribute__((ext_vector_type(4)));

__device__ __forceinline__ float bf2f(unsigned short u) {
  unsigned int x = ((unsigned int)u) << 16;
  return __uint_as_float(x);
}
__device__ __forceinline__ unsigned short f2bf(float f) {
  unsigned int x = __float_as_uint(f);
  unsigned int r = x + 0x7fffu + ((x >> 16) & 1u);   // round-to-nearest-even
  return (unsigned short)(r >> 16);
}

// split (a,b) into packed bf16 hi (RNE) and packed bf16 lo (residual)
__device__ __forceinline__ void split2(float a, float b, unsigned int& hi, unsigned int& lo) {
  float2 p = make_float2(a, b);
  __hip_bfloat162 hb = __float22bfloat162_rn(p);
  unsigned int hraw;
  memcpy(&hraw, &hb, 4);
  float2 hf = __bfloat1622float2(hb);
  float2 lf = make_float2(a - hf.x, b - hf.y);
  __hip_bfloat162 lb = __float22bfloat162_rn(lf);
  unsigned int lraw;
  memcpy(&lraw, &lb, 4);
  hi = hraw; lo = lraw;
}

// ---------------- small utility kernels ----------------

// zero only the atomic accumulators: sum1/sq1 [0,1200), sum2/sq2 [2400,3000)
// (scale2/shift2 [3000,3600) must survive: they carry prev layer's bn2)
__global__ void zero_stats_k(float* __restrict__ stats) {
  for (int i = threadIdx.x; i < 1200; i += blockDim.x) stats[i] = 0.0f;
  for (int i = threadIdx.x; i < 600; i += blockDim.x) stats[2400 + i] = 0.0f;
}

// preset identity bn for layer-0 input: scale2=1, shift2=0
__global__ void preset_ident_k(float* __restrict__ stats) {
  for (int i = threadIdx.x; i < 300; i += blockDim.x) {
    stats[3000 + i] = 1.0f;
    stats[3300 + i] = 0.0f;
  }
}

// agg = (1+eps[l]) * optrelu(zin*sc + sh)   (bn2 of previous layer fused in)
__global__ void init_agg_k(const float* __restrict__ zin, const float* __restrict__ sc,
                           const float* __restrict__ sh, const float* __restrict__ eps,
                           int l, int relu, float* __restrict__ agg) {
  float s = 1.0f + eps[l];
  int i = blockIdx.x * blockDim.x + threadIdx.x;
  const int n4 = NN * (EMBD / 4);
  if (i >= n4) return;
  int c4 = (i % (EMBD / 4)) * 4;
  float4 v = ((const float4*)zin)[i];
  float4 a = *(const float4*)(sc + c4);
  float4 b = *(const float4*)(sh + c4);
  v.x = v.x * a.x + b.x;
  v.y = v.y * a.y + b.y;
  v.z = v.z * a.z + b.z;
  v.w = v.w * a.w + b.w;
  if (relu) {
    v.x = fmaxf(v.x, 0.0f); v.y = fmaxf(v.y, 0.0f);
    v.z = fmaxf(v.z, 0.0f); v.w = fmaxf(v.w, 0.0f);
  }
  v.x *= s; v.y *= s; v.z *= s; v.w *= s;
  ((float4*)agg)[i] = v;
}

// one wave per edge: h[src] computed on-the-fly from zin (bn2+relu fused);
// msg = relu(h + tab[ea0] + tab[6+ea1]); atomicAdd into agg[dst]
__global__ void edge_scatter_k(const float* __restrict__ zin, const float* __restrict__ Wb_l,
                               const float* __restrict__ sc, const float* __restrict__ sh,
                               int relu,
                               const int* __restrict__ ei, const int* __restrict__ ea,
                               float* __restrict__ agg) {
  __shared__ float tab[EMBD * 9];
  __shared__ float scs[EMBD];
  __shared__ float shs[EMBD];
  for (int i = threadIdx.x; i < EMBD * 9; i += blockDim.x) tab[i] = Wb_l[i];
  for (int i = threadIdx.x; i < EMBD; i += blockDim.x) { scs[i] = sc[i]; shs[i] = sh[i]; }
  __syncthreads();
  int wave = threadIdx.x >> 6;
  int lane = threadIdx.x & 63;
  int e = blockIdx.x * 4 + wave;
  if (e >= NE) return;
  int src = ei[e];
  int dst = ei[NE + e];
  int t0 = ea[2 * e];
  int t1 = ea[2 * e + 1] + 6;
  const float* zs = zin + (size_t)src * EMBD;
  float* ad = agg + (size_t)dst * EMBD;
  for (int d = lane; d < EMBD; d += 64) {
    float hv = zs[d] * scs[d] + shs[d];
    if (relu) hv = fmaxf(hv, 0.0f);
    float m = hv + tab[d * 9 + t0] + tab[d * 9 + t1];
    if (m > 0.0f) atomicAdd(&ad[d], m);   // relu: zero contribution -> skip atomic
  }
}

// in-place: agg f32 -> per-element packed (hi | lo<<16) bf16 pair (same bytes)
__global__ void split_agg_k(unsigned int* __restrict__ a) {
  int i = blockIdx.x * blockDim.x + threadIdx.x;
  const int n4 = NN * (EMBD / 4);
  if (i >= n4) return;
  float4 v = ((const float4*)a)[i];
  unsigned int h0, l0, h1, l1;
  split2(v.x, v.y, h0, l0);
  split2(v.z, v.w, h1, l1);
  uint4 o;
  o.x = __builtin_amdgcn_perm(l0, h0, 0x05040100u);  // {hi_x, lo_x}
  o.y = __builtin_amdgcn_perm(l0, h0, 0x07060302u);  // {hi_y, lo_y}
  o.z = __builtin_amdgcn_perm(l1, h1, 0x05040100u);
  o.w = __builtin_amdgcn_perm(l1, h1, 0x07060302u);
  ((uint4*)a)[i] = o;
}

// scale/shift from accumulated sums
__global__ void finalize_k(const float* __restrict__ sum, const float* __restrict__ sq,
                           const float* __restrict__ g, const float* __restrict__ b,
                           float* __restrict__ scale, float* __restrict__ shift, int C) {
  int j = blockIdx.x * blockDim.x + threadIdx.x;
  if (j >= C) return;
  float mean = sum[j] * (1.0f / NN);
  float var = sq[j] * (1.0f / NN) - mean * mean;
  float sc = g[j] * rsqrtf(var + BNEPS);
  scale[j] = sc;
  shift[j] = b[j] - mean * sc;
}

// h = bn2(z2) (+relu) -- used only for the final layer output
__global__ void bn_apply_k(const float* __restrict__ z2, const float* __restrict__ scale,
                           const float* __restrict__ shift, int do_relu, float* __restrict__ out) {
  int i = blockIdx.x * blockDim.x + threadIdx.x;
  const int n4 = NN * (EMBD / 4);
  if (i >= n4) return;
  int c4 = (i % (EMBD / 4)) * 4;
  float4 v = ((const float4*)z2)[i];
  float4 sc = *(const float4*)(scale + c4);
  float4 sh = *(const float4*)(shift + c4);
  v.x = v.x * sc.x + sh.x;
  v.y = v.y * sc.y + sh.y;
  v.z = v.z * sc.z + sh.z;
  v.w = v.w * sc.w + sh.w;
  if (do_relu) {
    v.x = fmaxf(v.x, 0.0f); v.y = fmaxf(v.y, 0.0f);
    v.z = fmaxf(v.z, 0.0f); v.w = fmaxf(v.w, 0.0f);
  }
  ((float4*)out)[i] = v;
}

// ---------------- MFMA GEMMs ----------------
// 128x128 tile, BK=32, 256 threads (4 waves, 2x2 of 64x64 wave-tiles).
// A pre-split (hi|lo<<16 packed u32 per element, gemm1); B split at stage time.
// 3-term MFMA: acc += Ahi*Bhi + Alo*Bhi + Ahi*Blo (~f32 accuracy).
// LDS row stride 40 bf16 (pad 32->40): b128 frag reads 2-way aliased = free.
// gemm1 epilogue: assemble 128x128 bf16 tile in LDS (stride 136 shorts =
// 272B: 16B-aligned rows, quad writes 4-way aliased) then store dwordx4 --
// full 64B lines, no partial-line write amplification / RFO fills.

#define TM 128
#define TN 128
#define TK 32
#define LDT 40
#define OTS 136   // epilogue output tile stride (shorts)

// GEMM1: z1 = agg(M x 300) @ W1[l]^T + b1 ; z1 stored bf16 (RNE); column stats.
__global__ __launch_bounds__(256, 2) void gemm1_mfma_k(
    const unsigned int* __restrict__ A,  // M x 300, packed (hi|lo<<16)
    const float* __restrict__ W,         // 600 x 300 f32 (n-major, k contiguous)
    const float* __restrict__ bias,      // 600
    unsigned short* __restrict__ Z1,     // M x 600 bf16
    float* __restrict__ sumb, float* __restrict__ sqb) {
  const int M = NN, K = EMBD, NC = C1D;
  // 40960 B shared pool: staging (4 x 10240 B) during K-loop,
  // reused as 128 x OTS bf16 output tile (34816 B) in the epilogue.
  __shared__ unsigned short SM[20480];
  unsigned short* Ah = SM;
  unsigned short* Al = SM + 5120;
  unsigned short* Bh = SM + 10240;
  unsigned short* Bl = SM + 15360;
  unsigned short* OT = SM;

  int tid = threadIdx.x;
  int m0 = blockIdx.x * TM, n0 = blockIdx.y * TN;
  int w = tid >> 6, lane = tid & 63;
  int wm = w & 1, wn = w >> 1;
  int lm16 = lane & 15, quad = lane >> 4;

  f32x4 acc[4][4] = {};

  for (int k0 = 0; k0 < K; k0 += TK) {   // 10 steps
    // ---- stage A (packed hi/lo u32 -> two bf16 planes), 128 rows x 32 k
#pragma unroll
    for (int i = 0; i < 4; ++i) {
      int u = tid + i * 256;
      int row = u >> 3, q = u & 7;
      int k = k0 + q * 4;
      int m = m0 + row;
      uint4 x = make_uint4(0, 0, 0, 0);
      if (m < M && k + 3 < K) x = *(const uint4*)(A + (size_t)m * K + k);
      unsigned int h01 = __builtin_amdgcn_perm(x.y, x.x, 0x05040100u);
      unsigned int l01 = __builtin_amdgcn_perm(x.y, x.x, 0x07060302u);
      unsigned int h23 = __builtin_amdgcn_perm(x.w, x.z, 0x05040100u);
      unsigned int l23 = __builtin_amdgcn_perm(x.w, x.z, 0x07060302u);
      *(uint2*)&Ah[row * LDT + q * 4] = make_uint2(h01, h23);
      *(uint2*)&Al[row * LDT + q * 4] = make_uint2(l01, l23);
    }
    // ---- stage B (W rows are n, k contiguous)
#pragma unroll
    for (int i = 0; i < 4; ++i) {
      int u = tid + i * 256;
      int row = u >> 3, q = u & 7;
      int k = k0 + q * 4;
      int n = n0 + row;
      float4 v = make_float4(0, 0, 0, 0);
      if (n < NC && k + 3 < K) v = *(const float4*)(W + (size_t)n * K + k);
      unsigned int h0, l0, h1, l1;
      split2(v.x, v.y, h0, l0);
      split2(v.z, v.w, h1, l1);
      *(uint2*)&Bh[row * LDT + q * 4] = make_uint2(h0, h1);
      *(uint2*)&Bl[row * LDT + q * 4] = make_uint2(l0, l1);
    }
    __syncthreads();

    bf16x8 ah[4], al[4], bh[4], bl[4];
#pragma unroll
    for (int t = 0; t < 4; ++t) {
      int ar = (wm * 64 + t * 16 + lm16) * LDT + quad * 8;
      ah[t] = *(const bf16x8*)&Ah[ar];
      al[t] = *(const bf16x8*)&Al[ar];
      int br = (wn * 64 + t * 16 + lm16) * LDT + quad * 8;
      bh[t] = *(const bf16x8*)&Bh[br];
      bl[t] = *(const bf16x8*)&Bl[br];
    }
#pragma unroll
    for (int mt = 0; mt < 4; ++mt)
#pragma unroll
      for (int nt = 0; nt < 4; ++nt) {
        acc[mt][nt] = __builtin_amdgcn_mfma_f32_16x16x32_bf16(ah[mt], bh[nt], acc[mt][nt], 0, 0, 0);
        acc[mt][nt] = __builtin_amdgcn_mfma_f32_16x16x32_bf16(al[mt], bh[nt], acc[mt][nt], 0, 0, 0);
        acc[mt][nt] = __builtin_amdgcn_mfma_f32_16x16x32_bf16(ah[mt], bl[nt], acc[mt][nt], 0, 0, 0);
      }
    __syncthreads();
  }

  // ---- epilogue: bias + column stats from acc; bf16 tile to LDS
#pragma unroll
  for (int nt = 0; nt < 4; ++nt) {
    int c = n0 + wn * 64 + nt * 16 + lm16;
    bool cv = c < NC;
    float bs = cv ? bias[c] : 0.0f;
    int ocol = wn * 64 + nt * 16 + lm16;
    float csum = 0.0f, csq = 0.0f;
#pragma unroll
    for (int mt = 0; mt < 4; ++mt) {
      int rbase = m0 + wm * 64 + mt * 16 + quad * 4;
      int orow = wm * 64 + mt * 16 + quad * 4;
#pragma unroll
      for (int r = 0; r < 4; ++r) {
        float v = acc[mt][nt][r] + bs;
        OT[(orow + r) * OTS + ocol] = f2bf(v);
        if ((rbase + r) < M && cv) { csum += v; csq += v * v; }
      }
    }
    csum += __shfl_down(csum, 16); csum += __shfl_down(csum, 32);
    csq  += __shfl_down(csq, 16);  csq  += __shfl_down(csq, 32);
    if (quad == 0 && cv) {
      atomicAdd(&sumb[c], csum);
      atomicAdd(&sqb[c], csq);
    }
  }
  __syncthreads();

  // ---- cooperative coalesced store: full 64B lines (dwordx4 per lane)
  {
    int ncols = NC - n0; if (ncols > TN) ncols = TN;   // 128 or 88
    int nchunk = ncols >> 3;                           // 16 or 11 (8 bf16 per chunk)
    int cc = tid & 15;        // chunk id
    int rr0 = tid >> 4;       // starting row 0..15
    if (cc < nchunk) {
#pragma unroll
      for (int i = 0; i < 8; ++i) {
        int rr = rr0 + i * 16;
        int mm = m0 + rr;
        if (mm < M) {
          uint4 vv = *(const uint4*)&OT[rr * OTS + cc * 8];
          *(uint4*)&Z1[(size_t)mm * NC + n0 + cc * 8] = vv;
        }
      }
    }
  }
}

// GEMM2: z2 = relu(bn1(z1))(M x 600) @ W2[l]^T + b2 ; f32 out; column stats.
__global__ __launch_bounds__(256, 2) void gemm2_mfma_k(
    const unsigned short* __restrict__ Z1,   // M x 600 bf16 (raw pre-BN)
    const float* __restrict__ scale1, const float* __restrict__ shift1,  // 600
    const float* __restrict__ W,        // 300 x 600 f32 (n-major, k contiguous)
    const float* __restrict__ bias,     // 300
    float* __restrict__ Z2,             // M x 300 f32
    float* __restrict__ sumb, float* __restrict__ sqb) {
  const int M = NN, K = C1D, NC = EMBD;
  __shared__ unsigned short Ah[TM * LDT], Al[TM * LDT];
  __shared__ unsigned short Bh[TN * LDT], Bl[TN * LDT];

  int tid = threadIdx.x;
  int m0 = blockIdx.x * TM, n0 = blockIdx.y * TN;
  int w = tid >> 6, lane = tid & 63;
  int wm = w & 1, wn = w >> 1;
  int lm16 = lane & 15, quad = lane >> 4;

  f32x4 acc[4][4] = {};

  for (int k0 = 0; k0 < K; k0 += TK) {   // 19 steps (608 padded)
    // ---- stage A: z1 bf16 -> bn1+relu (f32) -> hi/lo split. 128 rows x 4 groups of 8
#pragma unroll
    for (int i = 0; i < 2; ++i) {
      int u = tid + i * 256;            // 0..511
      int row = u >> 2, g = u & 3;
      int k = k0 + g * 8;
      int m = m0 + row;
      float vals[8];
#pragma unroll
      for (int j = 0; j < 8; ++j) vals[j] = 0.0f;
      if (m < M) {
        if (k + 7 < K) {
          union { uint4 u4; unsigned short us[8]; } rr;
          rr.u4 = *(const uint4*)(Z1 + (size_t)m * K + k);
          float4 sc0 = *(const float4*)(scale1 + k);
          float4 sc1 = *(const float4*)(scale1 + k + 4);
          float4 sh0 = *(const float4*)(shift1 + k);
          float4 sh1 = *(const float4*)(shift1 + k + 4);
          const float* scp = &sc0.x; const float* shp = &sh0.x;
          const float* scq = &sc1.x; const float* shq = &sh1.x;
#pragma unroll
          for (int j = 0; j < 4; ++j) {
            vals[j]     = fmaxf(bf2f(rr.us[j])     * scp[j] + shp[j], 0.0f);
            vals[j + 4] = fmaxf(bf2f(rr.us[j + 4]) * scq[j] + shq[j], 0.0f);
          }
        } else {
#pragma unroll
          for (int j = 0; j < 8; ++j) {
            int kk = k + j;
            if (kk < K)
              vals[j] = fmaxf(bf2f(Z1[(size_t)m * K + kk]) * scale1[kk] + shift1[kk], 0.0f);
          }
        }
      }
      unsigned int h[4], l[4];
      split2(vals[0], vals[1], h[0], l[0]);
      split2(vals[2], vals[3], h[1], l[1]);
      split2(vals[4], vals[5], h[2], l[2]);
      split2(vals[6], vals[7], h[3], l[3]);
      *(uint4*)&Ah[row * LDT + g * 8] = make_uint4(h[0], h[1], h[2], h[3]);
      *(uint4*)&Al[row * LDT + g * 8] = make_uint4(l[0], l[1], l[2], l[3]);
    }
    // ---- stage B
#pragma unroll
    for (int i = 0; i < 4; ++i) {
      int u = tid + i * 256;
      int row = u >> 3, q = u & 7;
      int k = k0 + q * 4;
      int n = n0 + row;
      float4 v = make_float4(0, 0, 0, 0);
      if (n < NC) {
        if (k + 3 < K) v = *(const float4*)(W + (size_t)n * K + k);
        else {
          float* vv = &v.x;
#pragma unroll
          for (int j = 0; j < 4; ++j) if (k + j < K) vv[j] = W[(size_t)n * K + k + j];
        }
      }
      unsigned int h0, l0, h1, l1;
      split2(v.x, v.y, h0, l0);
      split2(v.z, v.w, h1, l1);
      *(uint2*)&Bh[row * LDT + q * 4] = make_uint2(h0, h1);
      *(uint2*)&Bl[row * LDT + q * 4] = make_uint2(l0, l1);
    }
    __syncthreads();

    bf16x8 ah[4], al[4], bh[4], bl[4];
#pragma unroll
    for (int t = 0; t < 4; ++t) {
      int ar = (wm * 64 + t * 16 + lm16) * LDT + quad * 8;
      ah[t] = *(const bf16x8*)&Ah[ar];
      al[t] = *(const bf16x8*)&Al[ar];
      int br = (wn * 64 + t * 16 + lm16) * LDT + quad * 8;
      bh[t] = *(const bf16x8*)&Bh[br];
      bl[t] = *(const bf16x8*)&Bl[br];
    }
#pragma unroll
    for (int mt = 0; mt < 4; ++mt)
#pragma unroll
      for (int nt = 0; nt < 4; ++nt) {
        acc[mt][nt] = __builtin_amdgcn_mfma_f32_16x16x32_bf16(ah[mt], bh[nt], acc[mt][nt], 0, 0, 0);
        acc[mt][nt] = __builtin_amdgcn_mfma_f32_16x16x32_bf16(al[mt], bh[nt], acc[mt][nt], 0, 0, 0);
        acc[mt][nt] = __builtin_amdgcn_mfma_f32_16x16x32_bf16(ah[mt], bl[nt], acc[mt][nt], 0, 0, 0);
      }
    __syncthreads();
  }

  // ---- epilogue: bias, f32 store (64B-aligned full lines), column stats
#pragma unroll
  for (int nt = 0; nt < 4; ++nt) {
    int c = n0 + wn * 64 + nt * 16 + lm16;
    bool cv = c < NC;
    float bs = cv ? bias[c] : 0.0f;
    float csum = 0.0f, csq = 0.0f;
#pragma unroll
    for (int mt = 0; mt < 4; ++mt) {
      int rbase = m0 + wm * 64 + mt * 16 + quad * 4;
#pragma unroll
      for (int r = 0; r < 4; ++r) {
        int mm = rbase + r;
        if (mm < M && cv) {
          float v = acc[mt][nt][r] + bs;
          Z2[(size_t)mm * NC + c] = v;
          csum += v; csq += v * v;
        }
      }
    }
    csum += __shfl_down(csum, 16); csum += __shfl_down(csum, 32);
    csq  += __shfl_down(csq, 16);  csq  += __shfl_down(csq, 32);
    if (quad == 0 && cv) {
      atomicAdd(&sumb[c], csum);
      atomicAdd(&sqb[c], csq);
    }
  }
}

// ---------------- host ----------------
// Region ping-pong (footprint unchanged: ws = N*300 f32 + 3600 stats floats):
//   layer l:  agg/z2 live in R(l) = (l even ? WS : OUT)
//             zin (=z2 of l-1, or x) and z1 live in the other region.
// bn2(+relu) of layer l-1 is applied on the fly by init_agg/edge_scatter using
// scale2/shift2 left in stats[3000/3300) (preset to identity for l=0 reading x).

extern "C" void kernel_launch(void* const* d_in, const int* in_sizes, int n_in,
                              void* d_out, int out_size, void* d_ws, size_t ws_size,
                              hipStream_t stream) {
  const float* x    = (const float*)d_in[0];
  const float* Wb   = (const float*)d_in[1];   // (L, 300, 9)
  const float* eps  = (const float*)d_in[2];   // (L,)
  const float* W1   = (const float*)d_in[3];   // (L, 600, 300)
  const float* b1   = (const float*)d_in[4];   // (L, 600)
  const float* bn1g = (const float*)d_in[5];
  const float* bn1b = (const float*)d_in[6];
  const float* W2   = (const float*)d_in[7];   // (L, 300, 600)
  const float* b2   = (const float*)d_in[8];   // (L, 300)
  const float* bng  = (const float*)d_in[9];
  const float* bnb  = (const float*)d_in[10];
  const int*   ei   = (const int*)d_in[11];    // (2, E)
  const int*   ea   = (const int*)d_in[12];    // (E, 2)

  float* WS  = (float*)d_ws;                   // N x 300 f32 region
  float* OUT = (float*)d_out;                  // N x 300 f32 region (final h)
  float* stats = (float*)d_ws + (size_t)NN * EMBD;
  // stats: [0,600) sum1 | [600,1200) sq1 | [1200,1800) scale1 | [1800,2400) shift1
  //        [2400,2700) sum2 | [2700,3000) sq2 | [3000,3300) scale2 | [3300,3600) shift2

  const int n4 = NN * (EMBD / 4);
  const int eltGrid = (n4 + 255) / 256;

  dim3 g1((NN + TM - 1) / TM, (C1D + TN - 1) / TN);   // 782 x 5
  dim3 g2((NN + TM - 1) / TM, (EMBD + TN - 1) / TN);  // 782 x 3

  preset_ident_k<<<1, 256, 0, stream>>>(stats);

  for (int l = 0; l < NL; ++l) {
    float* aggp = (l & 1) ? OUT : WS;     // agg -> z2
    float* z1p  = (l & 1) ? WS  : OUT;    // zin region, later z1
    const float* zin = (l == 0) ? x : (const float*)z1p;
    int relu_in = (l > 0) ? 1 : 0;        // zin from layers 0..3 always had relu

    zero_stats_k<<<1, 1024, 0, stream>>>(stats);
    init_agg_k<<<eltGrid, 256, 0, stream>>>(zin, stats + 3000, stats + 3300, eps, l, relu_in, aggp);
    edge_scatter_k<<<NE / 4, 256, 0, stream>>>(zin, Wb + (size_t)l * EMBD * 9,
                                               stats + 3000, stats + 3300, relu_in, ei, ea, aggp);
    split_agg_k<<<eltGrid, 256, 0, stream>>>((unsigned int*)aggp);
    gemm1_mfma_k<<<g1, 256, 0, stream>>>(
        (const unsigned int*)aggp, W1 + (size_t)l * C1D * EMBD, b1 + (size_t)l * C1D,
        (unsigned short*)z1p, stats + 0, stats + 600);
    finalize_k<<<3, 256, 0, stream>>>(stats + 0, stats + 600, bn1g + (size_t)l * C1D,
                                      bn1b + (size_t)l * C1D, stats + 1200, stats + 1800, C1D);
    gemm2_mfma_k<<<g2, 256, 0, stream>>>(
        (const unsigned short*)z1p, stats + 1200, stats + 1800,
        W2 + (size_t)l * EMBD * C1D, b2 + (size_t)l * EMBD,
        aggp, stats + 2400, stats + 2700);
    finalize_k<<<2, 256, 0, stream>>>(stats + 2400, stats + 2700, bng + (size_t)l * EMBD,
                                      bnb + (size_t)l * EMBD, stats + 3000, stats + 3300, EMBD);
  }
  // final output: h = bn2(z2_4), no relu; z2_4 lives in WS (l=4 even)
  bn_apply_k<<<eltGrid, 256, 0, stream>>>(WS, stats + 3000, stats + 3300, 0, OUT);
}

// Round 6
// 5341.474 us; speedup vs baseline: 1.2457x; 1.2457x over previous
//
#include <hip/hip_runtime.h>
#include <hip/hip_bf16.h>
#include <stdint.h>
#include <stddef.h>
#include <string.h>

#define NN 100000      // nodes
#define NE 256000      // edges
#define EMBD 300
#define C1D 600        // 2*EMB
#define NL 5
#define BNEPS 1e-5f

// replicated-stats block: per replica 1800 floats =
//   [0,600) sum1 | [600,1200) sq1 | [1200,1500) sum2 | [1500,1800) sq2
#define REPBLK 1800

typedef short bf16x8 __attribute__((ext_vector_type(8)));
typedef float f32x4 __attribute__((ext_vector_type(4)));

__device__ __forceinline__ float bf2f(unsigned short u) {
  unsigned int x = ((unsigned int)u) << 16;
  return __uint_as_float(x);
}
__device__ __forceinline__ unsigned short f2bf(float f) {
  unsigned int x = __float_as_uint(f);
  unsigned int r = x + 0x7fffu + ((x >> 16) & 1u);   // round-to-nearest-even
  return (unsigned short)(r >> 16);
}

// split (a,b) into packed bf16 hi (RNE) and packed bf16 lo (residual)
__device__ __forceinline__ void split2(float a, float b, unsigned int& hi, unsigned int& lo) {
  float2 p = make_float2(a, b);
  __hip_bfloat162 hb = __float22bfloat162_rn(p);
  unsigned int hraw;
  memcpy(&hraw, &hb, 4);
  float2 hf = __bfloat1622float2(hb);
  float2 lf = make_float2(a - hf.x, b - hf.y);
  __hip_bfloat162 lb = __float22bfloat162_rn(lf);
  unsigned int lraw;
  memcpy(&lraw, &lb, 4);
  hi = hraw; lo = lraw;
}

// ---------------- small utility kernels ----------------

// zero the replicated atomic accumulators (n = nrep*REPBLK floats)
__global__ void zero_stats_k(float* __restrict__ statrep, int n) {
  int i = blockIdx.x * blockDim.x + threadIdx.x;
  int stride = gridDim.x * blockDim.x;
  for (; i < n; i += stride) statrep[i] = 0.0f;
}

// preset identity bn for layer-0 input: scale2=1, shift2=0
__global__ void preset_ident_k(float* __restrict__ wsf) {
  for (int i = threadIdx.x; i < 300; i += blockDim.x) {
    wsf[1200 + i] = 1.0f;   // scale2
    wsf[1500 + i] = 0.0f;   // shift2
  }
}

// agg = (1+eps[l]) * optrelu(zin*sc + sh)   (bn2 of previous layer fused in)
__global__ void init_agg_k(const float* __restrict__ zin, const float* __restrict__ sc,
                           const float* __restrict__ sh, const float* __restrict__ eps,
                           int l, int relu, float* __restrict__ agg) {
  float s = 1.0f + eps[l];
  int i = blockIdx.x * blockDim.x + threadIdx.x;
  const int n4 = NN * (EMBD / 4);
  if (i >= n4) return;
  int c4 = (i % (EMBD / 4)) * 4;
  float4 v = ((const float4*)zin)[i];
  float4 a = *(const float4*)(sc + c4);
  float4 b = *(const float4*)(sh + c4);
  v.x = v.x * a.x + b.x;
  v.y = v.y * a.y + b.y;
  v.z = v.z * a.z + b.z;
  v.w = v.w * a.w + b.w;
  if (relu) {
    v.x = fmaxf(v.x, 0.0f); v.y = fmaxf(v.y, 0.0f);
    v.z = fmaxf(v.z, 0.0f); v.w = fmaxf(v.w, 0.0f);
  }
  v.x *= s; v.y *= s; v.z *= s; v.w *= s;
  ((float4*)agg)[i] = v;
}

// one wave per edge: h[src] computed on-the-fly from zin (bn2+relu fused);
// msg = relu(h + tab[ea0] + tab[6+ea1]); atomicAdd into agg[dst]
__global__ void edge_scatter_k(const float* __restrict__ zin, const float* __restrict__ Wb_l,
                               const float* __restrict__ sc, const float* __restrict__ sh,
                               int relu,
                               const int* __restrict__ ei, const int* __restrict__ ea,
                               float* __restrict__ agg) {
  __shared__ float tab[EMBD * 9];
  __shared__ float scs[EMBD];
  __shared__ float shs[EMBD];
  for (int i = threadIdx.x; i < EMBD * 9; i += blockDim.x) tab[i] = Wb_l[i];
  for (int i = threadIdx.x; i < EMBD; i += blockDim.x) { scs[i] = sc[i]; shs[i] = sh[i]; }
  __syncthreads();
  int wave = threadIdx.x >> 6;
  int lane = threadIdx.x & 63;
  int e = blockIdx.x * 4 + wave;
  if (e >= NE) return;
  int src = ei[e];
  int dst = ei[NE + e];
  int t0 = ea[2 * e];
  int t1 = ea[2 * e + 1] + 6;
  const float* zs = zin + (size_t)src * EMBD;
  float* ad = agg + (size_t)dst * EMBD;
  for (int d = lane; d < EMBD; d += 64) {
    float hv = zs[d] * scs[d] + shs[d];
    if (relu) hv = fmaxf(hv, 0.0f);
    float m = hv + tab[d * 9 + t0] + tab[d * 9 + t1];
    if (m > 0.0f) atomicAdd(&ad[d], m);   // relu: zero contribution -> skip atomic
  }
}

// in-place: agg f32 -> per-element packed (hi | lo<<16) bf16 pair (same bytes)
__global__ void split_agg_k(unsigned int* __restrict__ a) {
  int i = blockIdx.x * blockDim.x + threadIdx.x;
  const int n4 = NN * (EMBD / 4);
  if (i >= n4) return;
  float4 v = ((const float4*)a)[i];
  unsigned int h0, l0, h1, l1;
  split2(v.x, v.y, h0, l0);
  split2(v.z, v.w, h1, l1);
  uint4 o;
  o.x = __builtin_amdgcn_perm(l0, h0, 0x05040100u);  // {hi_x, lo_x}
  o.y = __builtin_amdgcn_perm(l0, h0, 0x07060302u);  // {hi_y, lo_y}
  o.z = __builtin_amdgcn_perm(l1, h1, 0x05040100u);
  o.w = __builtin_amdgcn_perm(l1, h1, 0x07060302u);
  ((uint4*)a)[i] = o;
}

// scale/shift from replicated accumulated sums
__global__ void finalize_k(const float* __restrict__ statrep, int off_sum, int off_sq,
                           int nrep,
                           const float* __restrict__ g, const float* __restrict__ b,
                           float* __restrict__ scale, float* __restrict__ shift, int C) {
  int j = blockIdx.x * blockDim.x + threadIdx.x;
  if (j >= C) return;
  float s = 0.0f, q = 0.0f;
  for (int r = 0; r < nrep; ++r) {
    const float* p = statrep + (size_t)r * REPBLK;
    s += p[off_sum + j];
    q += p[off_sq + j];
  }
  float mean = s * (1.0f / NN);
  float var = q * (1.0f / NN) - mean * mean;
  float sc = g[j] * rsqrtf(var + BNEPS);
  scale[j] = sc;
  shift[j] = b[j] - mean * sc;
}

// h = bn2(z2) (+relu) -- used only for the final layer output
__global__ void bn_apply_k(const float* __restrict__ z2, const float* __restrict__ scale,
                           const float* __restrict__ shift, int do_relu, float* __restrict__ out) {
  int i = blockIdx.x * blockDim.x + threadIdx.x;
  const int n4 = NN * (EMBD / 4);
  if (i >= n4) return;
  int c4 = (i % (EMBD / 4)) * 4;
  float4 v = ((const float4*)z2)[i];
  float4 sc = *(const float4*)(scale + c4);
  float4 sh = *(const float4*)(shift + c4);
  v.x = v.x * sc.x + sh.x;
  v.y = v.y * sc.y + sh.y;
  v.z = v.z * sc.z + sh.z;
  v.w = v.w * sc.w + sh.w;
  if (do_relu) {
    v.x = fmaxf(v.x, 0.0f); v.y = fmaxf(v.y, 0.0f);
    v.z = fmaxf(v.z, 0.0f); v.w = fmaxf(v.w, 0.0f);
  }
  ((float4*)out)[i] = v;
}

// ---------------- MFMA GEMMs ----------------
// 128x128 tile, BK=32, 256 threads (4 waves, 2x2 of 64x64 wave-tiles).
// A pre-split (hi|lo<<16 packed u32 per element, gemm1); B split at stage time.
// 3-term MFMA: acc += Ahi*Bhi + Alo*Bhi + Ahi*Blo (~f32 accuracy).
// LDS row stride 40 bf16 (pad 32->40): b128 frag reads 2-way aliased = free.
// Column stats go to a per-(blockIdx.x & repmask) replica of the stats block
// to kill same-line atomic serialization (19 cache lines shared by 3910
// blocks was the diagnosed constant-cost bottleneck).

#define TM 128
#define TN 128
#define TK 32
#define LDT 40
#define OTS 136   // epilogue output tile stride (shorts)

// GEMM1: z1 = agg(M x 300) @ W1[l]^T + b1 ; z1 stored bf16 (RNE); column stats.
__global__ __launch_bounds__(256, 2) void gemm1_mfma_k(
    const unsigned int* __restrict__ A,  // M x 300, packed (hi|lo<<16)
    const float* __restrict__ W,         // 600 x 300 f32 (n-major, k contiguous)
    const float* __restrict__ bias,      // 600
    unsigned short* __restrict__ Z1,     // M x 600 bf16
    float* __restrict__ statrep, int repmask) {
  const int M = NN, K = EMBD, NC = C1D;
  // 40960 B shared pool: staging (4 x 10240 B) during K-loop,
  // reused as 128 x OTS bf16 output tile (34816 B) in the epilogue.
  __shared__ unsigned short SM[20480];
  unsigned short* Ah = SM;
  unsigned short* Al = SM + 5120;
  unsigned short* Bh = SM + 10240;
  unsigned short* Bl = SM + 15360;
  unsigned short* OT = SM;

  int tid = threadIdx.x;
  int m0 = blockIdx.x * TM, n0 = blockIdx.y * TN;
  int w = tid >> 6, lane = tid & 63;
  int wm = w & 1, wn = w >> 1;
  int lm16 = lane & 15, quad = lane >> 4;

  f32x4 acc[4][4] = {};

  for (int k0 = 0; k0 < K; k0 += TK) {   // 10 steps
    // ---- stage A (packed hi/lo u32 -> two bf16 planes), 128 rows x 32 k
#pragma unroll
    for (int i = 0; i < 4; ++i) {
      int u = tid + i * 256;
      int row = u >> 3, q = u & 7;
      int k = k0 + q * 4;
      int m = m0 + row;
      uint4 x = make_uint4(0, 0, 0, 0);
      if (m < M && k + 3 < K) x = *(const uint4*)(A + (size_t)m * K + k);
      unsigned int h01 = __builtin_amdgcn_perm(x.y, x.x, 0x05040100u);
      unsigned int l01 = __builtin_amdgcn_perm(x.y, x.x, 0x07060302u);
      unsigned int h23 = __builtin_amdgcn_perm(x.w, x.z, 0x05040100u);
      unsigned int l23 = __builtin_amdgcn_perm(x.w, x.z, 0x07060302u);
      *(uint2*)&Ah[row * LDT + q * 4] = make_uint2(h01, h23);
      *(uint2*)&Al[row * LDT + q * 4] = make_uint2(l01, l23);
    }
    // ---- stage B (W rows are n, k contiguous)
#pragma unroll
    for (int i = 0; i < 4; ++i) {
      int u = tid + i * 256;
      int row = u >> 3, q = u & 7;
      int k = k0 + q * 4;
      int n = n0 + row;
      float4 v = make_float4(0, 0, 0, 0);
      if (n < NC && k + 3 < K) v = *(const float4*)(W + (size_t)n * K + k);
      unsigned int h0, l0, h1, l1;
      split2(v.x, v.y, h0, l0);
      split2(v.z, v.w, h1, l1);
      *(uint2*)&Bh[row * LDT + q * 4] = make_uint2(h0, h1);
      *(uint2*)&Bl[row * LDT + q * 4] = make_uint2(l0, l1);
    }
    __syncthreads();

    bf16x8 ah[4], al[4], bh[4], bl[4];
#pragma unroll
    for (int t = 0; t < 4; ++t) {
      int ar = (wm * 64 + t * 16 + lm16) * LDT + quad * 8;
      ah[t] = *(const bf16x8*)&Ah[ar];
      al[t] = *(const bf16x8*)&Al[ar];
      int br = (wn * 64 + t * 16 + lm16) * LDT + quad * 8;
      bh[t] = *(const bf16x8*)&Bh[br];
      bl[t] = *(const bf16x8*)&Bl[br];
    }
#pragma unroll
    for (int mt = 0; mt < 4; ++mt)
#pragma unroll
      for (int nt = 0; nt < 4; ++nt) {
        acc[mt][nt] = __builtin_amdgcn_mfma_f32_16x16x32_bf16(ah[mt], bh[nt], acc[mt][nt], 0, 0, 0);
        acc[mt][nt] = __builtin_amdgcn_mfma_f32_16x16x32_bf16(al[mt], bh[nt], acc[mt][nt], 0, 0, 0);
        acc[mt][nt] = __builtin_amdgcn_mfma_f32_16x16x32_bf16(ah[mt], bl[nt], acc[mt][nt], 0, 0, 0);
      }
    __syncthreads();
  }

  float* srep = statrep + (size_t)(blockIdx.x & repmask) * REPBLK;

  // ---- epilogue: bias + column stats from acc; bf16 tile to LDS
#pragma unroll
  for (int nt = 0; nt < 4; ++nt) {
    int c = n0 + wn * 64 + nt * 16 + lm16;
    bool cv = c < NC;
    float bs = cv ? bias[c] : 0.0f;
    int ocol = wn * 64 + nt * 16 + lm16;
    float csum = 0.0f, csq = 0.0f;
#pragma unroll
    for (int mt = 0; mt < 4; ++mt) {
      int rbase = m0 + wm * 64 + mt * 16 + quad * 4;
      int orow = wm * 64 + mt * 16 + quad * 4;
#pragma unroll
      for (int r = 0; r < 4; ++r) {
        float v = acc[mt][nt][r] + bs;
        OT[(orow + r) * OTS + ocol] = f2bf(v);
        if ((rbase + r) < M && cv) { csum += v; csq += v * v; }
      }
    }
    csum += __shfl_down(csum, 16); csum += __shfl_down(csum, 32);
    csq  += __shfl_down(csq, 16);  csq  += __shfl_down(csq, 32);
    if (quad == 0 && cv) {
      atomicAdd(&srep[c], csum);          // sum1
      atomicAdd(&srep[600 + c], csq);     // sq1
    }
  }
  __syncthreads();

  // ---- cooperative coalesced store: full 64B lines (dwordx4 per lane)
  {
    int ncols = NC - n0; if (ncols > TN) ncols = TN;   // 128 or 88
    int nchunk = ncols >> 3;                           // 16 or 11 (8 bf16 per chunk)
    int cc = tid & 15;        // chunk id
    int rr0 = tid >> 4;       // starting row 0..15
    if (cc < nchunk) {
#pragma unroll
      for (int i = 0; i < 8; ++i) {
        int rr = rr0 + i * 16;
        int mm = m0 + rr;
        if (mm < M) {
          uint4 vv = *(const uint4*)&OT[rr * OTS + cc * 8];
          *(uint4*)&Z1[(size_t)mm * NC + n0 + cc * 8] = vv;
        }
      }
    }
  }
}

// GEMM2: z2 = relu(bn1(z1))(M x 600) @ W2[l]^T + b2 ; f32 out; column stats.
__global__ __launch_bounds__(256, 2) void gemm2_mfma_k(
    const unsigned short* __restrict__ Z1,   // M x 600 bf16 (raw pre-BN)
    const float* __restrict__ scale1, const float* __restrict__ shift1,  // 600
    const float* __restrict__ W,        // 300 x 600 f32 (n-major, k contiguous)
    const float* __restrict__ bias,     // 300
    float* __restrict__ Z2,             // M x 300 f32
    float* __restrict__ statrep, int repmask) {
  const int M = NN, K = C1D, NC = EMBD;
  __shared__ unsigned short Ah[TM * LDT], Al[TM * LDT];
  __shared__ unsigned short Bh[TN * LDT], Bl[TN * LDT];

  int tid = threadIdx.x;
  int m0 = blockIdx.x * TM, n0 = blockIdx.y * TN;
  int w = tid >> 6, lane = tid & 63;
  int wm = w & 1, wn = w >> 1;
  int lm16 = lane & 15, quad = lane >> 4;

  f32x4 acc[4][4] = {};

  for (int k0 = 0; k0 < K; k0 += TK) {   // 19 steps (608 padded)
    // ---- stage A: z1 bf16 -> bn1+relu (f32) -> hi/lo split. 128 rows x 4 groups of 8
#pragma unroll
    for (int i = 0; i < 2; ++i) {
      int u = tid + i * 256;            // 0..511
      int row = u >> 2, g = u & 3;
      int k = k0 + g * 8;
      int m = m0 + row;
      float vals[8];
#pragma unroll
      for (int j = 0; j < 8; ++j) vals[j] = 0.0f;
      if (m < M) {
        if (k + 7 < K) {
          union { uint4 u4; unsigned short us[8]; } rr;
          rr.u4 = *(const uint4*)(Z1 + (size_t)m * K + k);
          float4 sc0 = *(const float4*)(scale1 + k);
          float4 sc1 = *(const float4*)(scale1 + k + 4);
          float4 sh0 = *(const float4*)(shift1 + k);
          float4 sh1 = *(const float4*)(shift1 + k + 4);
          const float* scp = &sc0.x; const float* shp = &sh0.x;
          const float* scq = &sc1.x; const float* shq = &sh1.x;
#pragma unroll
          for (int j = 0; j < 4; ++j) {
            vals[j]     = fmaxf(bf2f(rr.us[j])     * scp[j] + shp[j], 0.0f);
            vals[j + 4] = fmaxf(bf2f(rr.us[j + 4]) * scq[j] + shq[j], 0.0f);
          }
        } else {
#pragma unroll
          for (int j = 0; j < 8; ++j) {
            int kk = k + j;
            if (kk < K)
              vals[j] = fmaxf(bf2f(Z1[(size_t)m * K + kk]) * scale1[kk] + shift1[kk], 0.0f);
          }
        }
      }
      unsigned int h[4], l[4];
      split2(vals[0], vals[1], h[0], l[0]);
      split2(vals[2], vals[3], h[1], l[1]);
      split2(vals[4], vals[5], h[2], l[2]);
      split2(vals[6], vals[7], h[3], l[3]);
      *(uint4*)&Ah[row * LDT + g * 8] = make_uint4(h[0], h[1], h[2], h[3]);
      *(uint4*)&Al[row * LDT + g * 8] = make_uint4(l[0], l[1], l[2], l[3]);
    }
    // ---- stage B
#pragma unroll
    for (int i = 0; i < 4; ++i) {
      int u = tid + i * 256;
      int row = u >> 3, q = u & 7;
      int k = k0 + q * 4;
      int n = n0 + row;
      float4 v = make_float4(0, 0, 0, 0);
      if (n < NC) {
        if (k + 3 < K) v = *(const float4*)(W + (size_t)n * K + k);
        else {
          float* vv = &v.x;
#pragma unroll
          for (int j = 0; j < 4; ++j) if (k + j < K) vv[j] = W[(size_t)n * K + k + j];
        }
      }
      unsigned int h0, l0, h1, l1;
      split2(v.x, v.y, h0, l0);
      split2(v.z, v.w, h1, l1);
      *(uint2*)&Bh[row * LDT + q * 4] = make_uint2(h0, h1);
      *(uint2*)&Bl[row * LDT + q * 4] = make_uint2(l0, l1);
    }
    __syncthreads();

    bf16x8 ah[4], al[4], bh[4], bl[4];
#pragma unroll
    for (int t = 0; t < 4; ++t) {
      int ar = (wm * 64 + t * 16 + lm16) * LDT + quad * 8;
      ah[t] = *(const bf16x8*)&Ah[ar];
      al[t] = *(const bf16x8*)&Al[ar];
      int br = (wn * 64 + t * 16 + lm16) * LDT + quad * 8;
      bh[t] = *(const bf16x8*)&Bh[br];
      bl[t] = *(const bf16x8*)&Bl[br];
    }
#pragma unroll
    for (int mt = 0; mt < 4; ++mt)
#pragma unroll
      for (int nt = 0; nt < 4; ++nt) {
        acc[mt][nt] = __builtin_amdgcn_mfma_f32_16x16x32_bf16(ah[mt], bh[nt], acc[mt][nt], 0, 0, 0);
        acc[mt][nt] = __builtin_amdgcn_mfma_f32_16x16x32_bf16(al[mt], bh[nt], acc[mt][nt], 0, 0, 0);
        acc[mt][nt] = __builtin_amdgcn_mfma_f32_16x16x32_bf16(ah[mt], bl[nt], acc[mt][nt], 0, 0, 0);
      }
    __syncthreads();
  }

  float* srep = statrep + (size_t)(blockIdx.x & repmask) * REPBLK;

  // ---- epilogue: bias, f32 store (64B-aligned full lines), column stats
#pragma unroll
  for (int nt = 0; nt < 4; ++nt) {
    int c = n0 + wn * 64 + nt * 16 + lm16;
    bool cv = c < NC;
    float bs = cv ? bias[c] : 0.0f;
    float csum = 0.0f, csq = 0.0f;
#pragma unroll
    for (int mt = 0; mt < 4; ++mt) {
      int rbase = m0 + wm * 64 + mt * 16 + quad * 4;
#pragma unroll
      for (int r = 0; r < 4; ++r) {
        int mm = rbase + r;
        if (mm < M && cv) {
          float v = acc[mt][nt][r] + bs;
          Z2[(size_t)mm * NC + c] = v;
          csum += v; csq += v * v;
        }
      }
    }
    csum += __shfl_down(csum, 16); csum += __shfl_down(csum, 32);
    csq  += __shfl_down(csq, 16);  csq  += __shfl_down(csq, 32);
    if (quad == 0 && cv) {
      atomicAdd(&srep[1200 + c], csum);   // sum2
      atomicAdd(&srep[1500 + c], csq);    // sq2
    }
  }
}

// ---------------- host ----------------
// ws layout (floats): [0, NN*EMBD) agg/z2 region
//   wsf = ws + NN*EMBD:
//   wsf[0,600) scale1 | [600,1200) shift1 | [1200,1500) scale2 | [1500,1800) shift2
//   wsf[1800 ...): nrep replicas of REPBLK-float stat accumulators
// nrep = 64 if ws_size allows, else 1 (fallback = previous behavior size).

extern "C" void kernel_launch(void* const* d_in, const int* in_sizes, int n_in,
                              void* d_out, int out_size, void* d_ws, size_t ws_size,
                              hipStream_t stream) {
  const float* x    = (const float*)d_in[0];
  const float* Wb   = (const float*)d_in[1];   // (L, 300, 9)
  const float* eps  = (const float*)d_in[2];   // (L,)
  const float* W1   = (const float*)d_in[3];   // (L, 600, 300)
  const float* b1   = (const float*)d_in[4];   // (L, 600)
  const float* bn1g = (const float*)d_in[5];
  const float* bn1b = (const float*)d_in[6];
  const float* W2   = (const float*)d_in[7];   // (L, 300, 600)
  const float* b2   = (const float*)d_in[8];   // (L, 300)
  const float* bng  = (const float*)d_in[9];
  const float* bnb  = (const float*)d_in[10];
  const int*   ei   = (const int*)d_in[11];    // (2, E)
  const int*   ea   = (const int*)d_in[12];    // (E, 2)

  float* WS  = (float*)d_ws;                   // N x 300 f32 region
  float* OUT = (float*)d_out;                  // N x 300 f32 region (final h)
  float* wsf = (float*)d_ws + (size_t)NN * EMBD;
  float* statrep = wsf + 1800;

  size_t need64 = ((size_t)NN * EMBD + 1800 + (size_t)64 * REPBLK) * sizeof(float);
  int nrep = (ws_size >= need64) ? 64 : 1;
  int repmask = nrep - 1;
  int zn = nrep * REPBLK;

  const int n4 = NN * (EMBD / 4);
  const int eltGrid = (n4 + 255) / 256;

  dim3 g1((NN + TM - 1) / TM, (C1D + TN - 1) / TN);   // 782 x 5
  dim3 g2((NN + TM - 1) / TM, (EMBD + TN - 1) / TN);  // 782 x 3

  preset_ident_k<<<1, 256, 0, stream>>>(wsf);

  for (int l = 0; l < NL; ++l) {
    float* aggp = (l & 1) ? OUT : WS;     // agg -> z2
    float* z1p  = (l & 1) ? WS  : OUT;    // zin region, later z1
    const float* zin = (l == 0) ? x : (const float*)z1p;
    int relu_in = (l > 0) ? 1 : 0;        // zin from layers 0..3 always had relu

    zero_stats_k<<<64, 256, 0, stream>>>(statrep, zn);
    init_agg_k<<<eltGrid, 256, 0, stream>>>(zin, wsf + 1200, wsf + 1500, eps, l, relu_in, aggp);
    edge_scatter_k<<<NE / 4, 256, 0, stream>>>(zin, Wb + (size_t)l * EMBD * 9,
                                               wsf + 1200, wsf + 1500, relu_in, ei, ea, aggp);
    split_agg_k<<<eltGrid, 256, 0, stream>>>((unsigned int*)aggp);
    gemm1_mfma_k<<<g1, 256, 0, stream>>>(
        (const unsigned int*)aggp, W1 + (size_t)l * C1D * EMBD, b1 + (size_t)l * C1D,
        (unsigned short*)z1p, statrep, repmask);
    finalize_k<<<3, 256, 0, stream>>>(statrep, 0, 600, nrep, bn1g + (size_t)l * C1D,
                                      bn1b + (size_t)l * C1D, wsf + 0, wsf + 600, C1D);
    gemm2_mfma_k<<<g2, 256, 0, stream>>>(
        (const unsigned short*)z1p, wsf + 0, wsf + 600,
        W2 + (size_t)l * EMBD * C1D, b2 + (size_t)l * EMBD,
        aggp, statrep, repmask);
    finalize_k<<<2, 256, 0, stream>>>(statrep, 1200, 1500, nrep, bng + (size_t)l * EMBD,
                                      bnb + (size_t)l * EMBD, wsf + 1200, wsf + 1500, EMBD);
  }
  // final output: h = bn2(z2_4), no relu; z2_4 lives in WS (l=4 even)
  bn_apply_k<<<eltGrid, 256, 0, stream>>>(WS, wsf + 1200, wsf + 1500, 0, OUT);
}

// Round 7
// 4700.340 us; speedup vs baseline: 1.4156x; 1.1364x over previous
//
#include <hip/hip_runtime.h>
#include <hip/hip_bf16.h>
#include <stdint.h>
#include <stddef.h>
#include <string.h>

#define NN 100000      // nodes
#define NE 256000      // edges
#define EMBD 300
#define C1D 600        // 2*EMB
#define NL 5
#define BNEPS 1e-5f

// replicated-stats block: per replica 1800 floats =
//   [0,600) sum1 | [600,1200) sq1 | [1200,1500) sum2 | [1500,1800) sq2
#define REPBLK 1800

typedef short bf16x8 __attribute__((ext_vector_type(8)));
typedef float f32x4 __attribute__((ext_vector_type(4)));

__device__ __forceinline__ float bf2f(unsigned short u) {
  unsigned int x = ((unsigned int)u) << 16;
  return __uint_as_float(x);
}
__device__ __forceinline__ unsigned short f2bf(float f) {
  unsigned int x = __float_as_uint(f);
  unsigned int r = x + 0x7fffu + ((x >> 16) & 1u);   // round-to-nearest-even
  return (unsigned short)(r >> 16);
}

// split (a,b) into packed bf16 hi (RNE) and packed bf16 lo (residual)
__device__ __forceinline__ void split2(float a, float b, unsigned int& hi, unsigned int& lo) {
  float2 p = make_float2(a, b);
  __hip_bfloat162 hb = __float22bfloat162_rn(p);
  unsigned int hraw;
  memcpy(&hraw, &hb, 4);
  float2 hf = __bfloat1622float2(hb);
  float2 lf = make_float2(a - hf.x, b - hf.y);
  __hip_bfloat162 lb = __float22bfloat162_rn(lf);
  unsigned int lraw;
  memcpy(&lraw, &lb, 4);
  hi = hraw; lo = lraw;
}

// bijective XCD-chunked swizzle: consecutive dispatch ids land on XCD id%8;
// remap so each XCD owns a contiguous swz-range, then y-fastest within swz so
// the GY blocks sharing an A-tile are consecutive AND co-XCD (L2 reuse).
__device__ __forceinline__ void swizzle_xy(int GX, int GY, int& tx, int& ty) {
  int nwg = GX * GY;
  int bid = blockIdx.y * GX + blockIdx.x;   // ~dispatch order (x fastest)
  int xcd = bid & 7, local = bid >> 3;
  int q = nwg >> 3, r = nwg & 7;
  int swz = (xcd < r) ? (xcd * (q + 1) + local)
                      : (r * (q + 1) + (xcd - r) * q + local);
  tx = swz / GY;
  ty = swz - tx * GY;
}

// ---------------- small utility kernels ----------------

// zero the replicated atomic accumulators (n = nrep*REPBLK floats)
__global__ void zero_stats_k(float* __restrict__ statrep, int n) {
  int i = blockIdx.x * blockDim.x + threadIdx.x;
  int stride = gridDim.x * blockDim.x;
  for (; i < n; i += stride) statrep[i] = 0.0f;
}

// preset identity bn for layer-0 input: scale2=1, shift2=0
__global__ void preset_ident_k(float* __restrict__ wsf) {
  for (int i = threadIdx.x; i < 300; i += blockDim.x) {
    wsf[1200 + i] = 1.0f;   // scale2
    wsf[1500 + i] = 0.0f;   // shift2
  }
}

// agg = (1+eps[l]) * optrelu(zin*sc + sh)   (bn2 of previous layer fused in)
__global__ void init_agg_k(const float* __restrict__ zin, const float* __restrict__ sc,
                           const float* __restrict__ sh, const float* __restrict__ eps,
                           int l, int relu, float* __restrict__ agg) {
  float s = 1.0f + eps[l];
  int i = blockIdx.x * blockDim.x + threadIdx.x;
  const int n4 = NN * (EMBD / 4);
  if (i >= n4) return;
  int c4 = (i % (EMBD / 4)) * 4;
  float4 v = ((const float4*)zin)[i];
  float4 a = *(const float4*)(sc + c4);
  float4 b = *(const float4*)(sh + c4);
  v.x = v.x * a.x + b.x;
  v.y = v.y * a.y + b.y;
  v.z = v.z * a.z + b.z;
  v.w = v.w * a.w + b.w;
  if (relu) {
    v.x = fmaxf(v.x, 0.0f); v.y = fmaxf(v.y, 0.0f);
    v.z = fmaxf(v.z, 0.0f); v.w = fmaxf(v.w, 0.0f);
  }
  v.x *= s; v.y *= s; v.z *= s; v.w *= s;
  ((float4*)agg)[i] = v;
}

// one wave per edge: h[src] computed on-the-fly from zin (bn2+relu fused);
// msg = relu(h + tab[ea0] + tab[6+ea1]); atomicAdd into agg[dst]
__global__ void edge_scatter_k(const float* __restrict__ zin, const float* __restrict__ Wb_l,
                               const float* __restrict__ sc, const float* __restrict__ sh,
                               int relu,
                               const int* __restrict__ ei, const int* __restrict__ ea,
                               float* __restrict__ agg) {
  __shared__ float tab[EMBD * 9];
  __shared__ float scs[EMBD];
  __shared__ float shs[EMBD];
  for (int i = threadIdx.x; i < EMBD * 9; i += blockDim.x) tab[i] = Wb_l[i];
  for (int i = threadIdx.x; i < EMBD; i += blockDim.x) { scs[i] = sc[i]; shs[i] = sh[i]; }
  __syncthreads();
  int wave = threadIdx.x >> 6;
  int lane = threadIdx.x & 63;
  int e = blockIdx.x * 4 + wave;
  if (e >= NE) return;
  int src = ei[e];
  int dst = ei[NE + e];
  int t0 = ea[2 * e];
  int t1 = ea[2 * e + 1] + 6;
  const float* zs = zin + (size_t)src * EMBD;
  float* ad = agg + (size_t)dst * EMBD;
  for (int d = lane; d < EMBD; d += 64) {
    float hv = zs[d] * scs[d] + shs[d];
    if (relu) hv = fmaxf(hv, 0.0f);
    float m = hv + tab[d * 9 + t0] + tab[d * 9 + t1];
    if (m > 0.0f) atomicAdd(&ad[d], m);   // relu: zero contribution -> skip atomic
  }
}

// in-place: agg f32 -> per-element packed (hi | lo<<16) bf16 pair (same bytes)
__global__ void split_agg_k(unsigned int* __restrict__ a) {
  int i = blockIdx.x * blockDim.x + threadIdx.x;
  const int n4 = NN * (EMBD / 4);
  if (i >= n4) return;
  float4 v = ((const float4*)a)[i];
  unsigned int h0, l0, h1, l1;
  split2(v.x, v.y, h0, l0);
  split2(v.z, v.w, h1, l1);
  uint4 o;
  o.x = __builtin_amdgcn_perm(l0, h0, 0x05040100u);  // {hi_x, lo_x}
  o.y = __builtin_amdgcn_perm(l0, h0, 0x07060302u);  // {hi_y, lo_y}
  o.z = __builtin_amdgcn_perm(l1, h1, 0x05040100u);
  o.w = __builtin_amdgcn_perm(l1, h1, 0x07060302u);
  ((uint4*)a)[i] = o;
}

// scale/shift from replicated accumulated sums
__global__ void finalize_k(const float* __restrict__ statrep, int off_sum, int off_sq,
                           int nrep,
                           const float* __restrict__ g, const float* __restrict__ b,
                           float* __restrict__ scale, float* __restrict__ shift, int C) {
  int j = blockIdx.x * blockDim.x + threadIdx.x;
  if (j >= C) return;
  float s = 0.0f, q = 0.0f;
  for (int r = 0; r < nrep; ++r) {
    const float* p = statrep + (size_t)r * REPBLK;
    s += p[off_sum + j];
    q += p[off_sq + j];
  }
  float mean = s * (1.0f / NN);
  float var = q * (1.0f / NN) - mean * mean;
  float sc = g[j] * rsqrtf(var + BNEPS);
  scale[j] = sc;
  shift[j] = b[j] - mean * sc;
}

// h = bn2(z2) (+relu) -- used only for the final layer output
__global__ void bn_apply_k(const float* __restrict__ z2, const float* __restrict__ scale,
                           const float* __restrict__ shift, int do_relu, float* __restrict__ out) {
  int i = blockIdx.x * blockDim.x + threadIdx.x;
  const int n4 = NN * (EMBD / 4);
  if (i >= n4) return;
  int c4 = (i % (EMBD / 4)) * 4;
  float4 v = ((const float4*)z2)[i];
  float4 sc = *(const float4*)(scale + c4);
  float4 sh = *(const float4*)(shift + c4);
  v.x = v.x * sc.x + sh.x;
  v.y = v.y * sc.y + sh.y;
  v.z = v.z * sc.z + sh.z;
  v.w = v.w * sc.w + sh.w;
  if (do_relu) {
    v.x = fmaxf(v.x, 0.0f); v.y = fmaxf(v.y, 0.0f);
    v.z = fmaxf(v.z, 0.0f); v.w = fmaxf(v.w, 0.0f);
  }
  ((float4*)out)[i] = v;
}

// ---------------- MFMA GEMMs ----------------
// 128x128 tile, BK=32, 256 threads (4 waves, 2x2 of 64x64 wave-tiles).
// A pre-split (hi|lo<<16 packed u32 per element, gemm1); B split at stage time.
// 3-term MFMA: acc += Ahi*Bhi + Alo*Bhi + Ahi*Blo (~f32 accuracy).
// LDS row stride 40 bf16 (pad 32->40): b128 frag reads 2-way aliased = free.
// Pipeline per K-step: {write regs->LDS} bar {issue t+1 loads; ds_read+MFMA}
// bar -- the prefetch loads fly during the MFMA phase, so barrier-2's vmcnt
// drain finds them landed (load latency hidden without inline asm).
// XCD-chunked y-inner swizzle: GY co-A-tile blocks are consecutive + co-XCD.

#define TM 128
#define TN 128
#define TK 32
#define LDT 40
#define OTS 136   // epilogue output tile stride (shorts)

// GEMM1: z1 = agg(M x 300) @ W1[l]^T + b1 ; z1 stored bf16 (RNE); column stats.
__global__ __launch_bounds__(256, 2) void gemm1_mfma_k(
    const unsigned int* __restrict__ A,  // M x 300, packed (hi|lo<<16)
    const float* __restrict__ W,         // 600 x 300 f32 (n-major, k contiguous)
    const float* __restrict__ bias,      // 600
    unsigned short* __restrict__ Z1,     // M x 600 bf16
    float* __restrict__ statrep, int repmask) {
  const int M = NN, K = EMBD, NC = C1D;
  // 40960 B shared pool: staging (4 x 10240 B) during K-loop,
  // reused as 128 x OTS bf16 output tile (34816 B) in the epilogue.
  __shared__ unsigned short SM[20480];
  unsigned short* Ah = SM;
  unsigned short* Al = SM + 5120;
  unsigned short* Bh = SM + 10240;
  unsigned short* Bl = SM + 15360;
  unsigned short* OT = SM;

  int tid = threadIdx.x;
  int tx, ty;
  swizzle_xy(gridDim.x, gridDim.y, tx, ty);
  int m0 = tx * TM, n0 = ty * TN;
  int w = tid >> 6, lane = tid & 63;
  int wm = w & 1, wn = w >> 1;
  int lm16 = lane & 15, quad = lane >> 4;
  int srow = tid >> 3, sq = tid & 7;   // staging: rows srow+i*32, k-group sq

  f32x4 acc[4][4] = {};
  uint4 pA[4];
  float4 pB[4];

  // preload K-step 0
#pragma unroll
  for (int i = 0; i < 4; ++i) {
    int row = srow + i * 32;
    int k = sq * 4;
    int m = m0 + row, n = n0 + row;
    uint4 xa = make_uint4(0, 0, 0, 0);
    if (m < M && k + 3 < K) xa = *(const uint4*)(A + (size_t)m * K + k);
    pA[i] = xa;
    float4 vb = make_float4(0, 0, 0, 0);
    if (n < NC && k + 3 < K) vb = *(const float4*)(W + (size_t)n * K + k);
    pB[i] = vb;
  }

  for (int k0 = 0; k0 < K; k0 += TK) {   // 10 steps
    // ---- write phase: regs -> hi/lo planes in LDS
#pragma unroll
    for (int i = 0; i < 4; ++i) {
      int row = srow + i * 32;
      uint4 x = pA[i];
      unsigned int h01 = __builtin_amdgcn_perm(x.y, x.x, 0x05040100u);
      unsigned int l01 = __builtin_amdgcn_perm(x.y, x.x, 0x07060302u);
      unsigned int h23 = __builtin_amdgcn_perm(x.w, x.z, 0x05040100u);
      unsigned int l23 = __builtin_amdgcn_perm(x.w, x.z, 0x07060302u);
      *(uint2*)&Ah[row * LDT + sq * 4] = make_uint2(h01, h23);
      *(uint2*)&Al[row * LDT + sq * 4] = make_uint2(l01, l23);
      float4 v = pB[i];
      unsigned int bh0, bl0, bh1, bl1;
      split2(v.x, v.y, bh0, bl0);
      split2(v.z, v.w, bh1, bl1);
      *(uint2*)&Bh[row * LDT + sq * 4] = make_uint2(bh0, bh1);
      *(uint2*)&Bl[row * LDT + sq * 4] = make_uint2(bl0, bl1);
    }
    __syncthreads();

    // ---- issue next K-step's loads (fly during MFMA phase)
    if (k0 + TK < K) {
      int kn = k0 + TK;
#pragma unroll
      for (int i = 0; i < 4; ++i) {
        int row = srow + i * 32;
        int k = kn + sq * 4;
        int m = m0 + row, n = n0 + row;
        uint4 xa = make_uint4(0, 0, 0, 0);
        if (m < M && k + 3 < K) xa = *(const uint4*)(A + (size_t)m * K + k);
        pA[i] = xa;
        float4 vb = make_float4(0, 0, 0, 0);
        if (n < NC && k + 3 < K) vb = *(const float4*)(W + (size_t)n * K + k);
        pB[i] = vb;
      }
    }

    bf16x8 ah[4], al[4], bh[4], bl[4];
#pragma unroll
    for (int t = 0; t < 4; ++t) {
      int ar = (wm * 64 + t * 16 + lm16) * LDT + quad * 8;
      ah[t] = *(const bf16x8*)&Ah[ar];
      al[t] = *(const bf16x8*)&Al[ar];
      int br = (wn * 64 + t * 16 + lm16) * LDT + quad * 8;
      bh[t] = *(const bf16x8*)&Bh[br];
      bl[t] = *(const bf16x8*)&Bl[br];
    }
#pragma unroll
    for (int mt = 0; mt < 4; ++mt)
#pragma unroll
      for (int nt = 0; nt < 4; ++nt) {
        acc[mt][nt] = __builtin_amdgcn_mfma_f32_16x16x32_bf16(ah[mt], bh[nt], acc[mt][nt], 0, 0, 0);
        acc[mt][nt] = __builtin_amdgcn_mfma_f32_16x16x32_bf16(al[mt], bh[nt], acc[mt][nt], 0, 0, 0);
        acc[mt][nt] = __builtin_amdgcn_mfma_f32_16x16x32_bf16(ah[mt], bl[nt], acc[mt][nt], 0, 0, 0);
      }
    __syncthreads();
  }

  float* srep = statrep + (size_t)(blockIdx.x & repmask) * REPBLK;

  // ---- epilogue: bias + column stats from acc; bf16 tile to LDS
#pragma unroll
  for (int nt = 0; nt < 4; ++nt) {
    int c = n0 + wn * 64 + nt * 16 + lm16;
    bool cv = c < NC;
    float bs = cv ? bias[c] : 0.0f;
    int ocol = wn * 64 + nt * 16 + lm16;
    float csum = 0.0f, csq = 0.0f;
#pragma unroll
    for (int mt = 0; mt < 4; ++mt) {
      int rbase = m0 + wm * 64 + mt * 16 + quad * 4;
      int orow = wm * 64 + mt * 16 + quad * 4;
#pragma unroll
      for (int r = 0; r < 4; ++r) {
        float v = acc[mt][nt][r] + bs;
        OT[(orow + r) * OTS + ocol] = f2bf(v);
        if ((rbase + r) < M && cv) { csum += v; csq += v * v; }
      }
    }
    csum += __shfl_down(csum, 16); csum += __shfl_down(csum, 32);
    csq  += __shfl_down(csq, 16);  csq  += __shfl_down(csq, 32);
    if (quad == 0 && cv) {
      atomicAdd(&srep[c], csum);          // sum1
      atomicAdd(&srep[600 + c], csq);     // sq1
    }
  }
  __syncthreads();

  // ---- cooperative coalesced store: full 64B lines (dwordx4 per lane)
  {
    int ncols = NC - n0; if (ncols > TN) ncols = TN;   // 128 or 88
    int nchunk = ncols >> 3;                           // 16 or 11 (8 bf16 per chunk)
    int cc = tid & 15;        // chunk id
    int rr0 = tid >> 4;       // starting row 0..15
    if (cc < nchunk) {
#pragma unroll
      for (int i = 0; i < 8; ++i) {
        int rr = rr0 + i * 16;
        int mm = m0 + rr;
        if (mm < M) {
          uint4 vv = *(const uint4*)&OT[rr * OTS + cc * 8];
          *(uint4*)&Z1[(size_t)mm * NC + n0 + cc * 8] = vv;
        }
      }
    }
  }
}

// GEMM2: z2 = relu(bn1(z1))(M x 600) @ W2[l]^T + b2 ; f32 out; column stats.
__global__ __launch_bounds__(256, 2) void gemm2_mfma_k(
    const unsigned short* __restrict__ Z1,   // M x 600 bf16 (raw pre-BN)
    const float* __restrict__ scale1, const float* __restrict__ shift1,  // 600
    const float* __restrict__ W,        // 300 x 600 f32 (n-major, k contiguous)
    const float* __restrict__ bias,     // 300
    float* __restrict__ Z2,             // M x 300 f32
    float* __restrict__ statrep, int repmask) {
  const int M = NN, K = C1D, NC = EMBD;
  __shared__ unsigned short Ah[TM * LDT], Al[TM * LDT];
  __shared__ unsigned short Bh[TN * LDT], Bl[TN * LDT];

  int tid = threadIdx.x;
  int tx, ty;
  swizzle_xy(gridDim.x, gridDim.y, tx, ty);
  int m0 = tx * TM, n0 = ty * TN;
  int w = tid >> 6, lane = tid & 63;
  int wm = w & 1, wn = w >> 1;
  int lm16 = lane & 15, quad = lane >> 4;
  int arow = tid >> 2, ag = tid & 3;   // A stage: rows arow+i*64, k-group ag (8 wide)
  int brow = tid >> 3, bq = tid & 7;   // B stage: rows brow+i*32, k-group bq (4 wide)

  f32x4 acc[4][4] = {};
  uint4 pA[2];
  float4 pB[4];

  // preload K-step 0  (K=600 is a multiple of 8/4: vectors never straddle)
#pragma unroll
  for (int i = 0; i < 2; ++i) {
    int row = arow + i * 64;
    int k = ag * 8;
    int m = m0 + row;
    uint4 xa = make_uint4(0, 0, 0, 0);
    if (m < M && k + 7 < K) xa = *(const uint4*)(Z1 + (size_t)m * K + k);
    pA[i] = xa;
  }
#pragma unroll
  for (int i = 0; i < 4; ++i) {
    int row = brow + i * 32;
    int k = bq * 4;
    int n = n0 + row;
    float4 vb = make_float4(0, 0, 0, 0);
    if (n < NC && k + 3 < K) vb = *(const float4*)(W + (size_t)n * K + k);
    pB[i] = vb;
  }

  for (int k0 = 0; k0 < K; k0 += TK) {   // 19 steps (608 padded)
    // ---- write phase A: bn1+relu+split from prefetched z1 regs
#pragma unroll
    for (int i = 0; i < 2; ++i) {
      int row = arow + i * 64;
      int k = k0 + ag * 8;
      int m = m0 + row;
      float vals[8];
#pragma unroll
      for (int j = 0; j < 8; ++j) vals[j] = 0.0f;
      if (m < M && k + 7 < K) {
        union { uint4 u4; unsigned short us[8]; } rr;
        rr.u4 = pA[i];
        float4 sc0 = *(const float4*)(scale1 + k);
        float4 sc1 = *(const float4*)(scale1 + k + 4);
        float4 sh0 = *(const float4*)(shift1 + k);
        float4 sh1 = *(const float4*)(shift1 + k + 4);
        const float* scp = &sc0.x; const float* shp = &sh0.x;
        const float* scq = &sc1.x; const float* shq = &sh1.x;
#pragma unroll
        for (int j = 0; j < 4; ++j) {
          vals[j]     = fmaxf(bf2f(rr.us[j])     * scp[j] + shp[j], 0.0f);
          vals[j + 4] = fmaxf(bf2f(rr.us[j + 4]) * scq[j] + shq[j], 0.0f);
        }
      }
      unsigned int h[4], l[4];
      split2(vals[0], vals[1], h[0], l[0]);
      split2(vals[2], vals[3], h[1], l[1]);
      split2(vals[4], vals[5], h[2], l[2]);
      split2(vals[6], vals[7], h[3], l[3]);
      *(uint4*)&Ah[row * LDT + ag * 8] = make_uint4(h[0], h[1], h[2], h[3]);
      *(uint4*)&Al[row * LDT + ag * 8] = make_uint4(l[0], l[1], l[2], l[3]);
    }
    // ---- write phase B
#pragma unroll
    for (int i = 0; i < 4; ++i) {
      int row = brow + i * 32;
      float4 v = pB[i];
      unsigned int h0, l0, h1, l1;
      split2(v.x, v.y, h0, l0);
      split2(v.z, v.w, h1, l1);
      *(uint2*)&Bh[row * LDT + bq * 4] = make_uint2(h0, h1);
      *(uint2*)&Bl[row * LDT + bq * 4] = make_uint2(l0, l1);
    }
    __syncthreads();

    // ---- issue next K-step's loads (fly during MFMA phase)
    if (k0 + TK < K) {
      int kn = k0 + TK;
#pragma unroll
      for (int i = 0; i < 2; ++i) {
        int row = arow + i * 64;
        int k = kn + ag * 8;
        int m = m0 + row;
        uint4 xa = make_uint4(0, 0, 0, 0);
        if (m < M && k + 7 < K) xa = *(const uint4*)(Z1 + (size_t)m * K + k);
        pA[i] = xa;
      }
#pragma unroll
      for (int i = 0; i < 4; ++i) {
        int row = brow + i * 32;
        int k = kn + bq * 4;
        int n = n0 + row;
        float4 vb = make_float4(0, 0, 0, 0);
        if (n < NC && k + 3 < K) vb = *(const float4*)(W + (size_t)n * K + k);
        pB[i] = vb;
      }
    }

    bf16x8 ah[4], al[4], bh[4], bl[4];
#pragma unroll
    for (int t = 0; t < 4; ++t) {
      int ar = (wm * 64 + t * 16 + lm16) * LDT + quad * 8;
      ah[t] = *(const bf16x8*)&Ah[ar];
      al[t] = *(const bf16x8*)&Al[ar];
      int br = (wn * 64 + t * 16 + lm16) * LDT + quad * 8;
      bh[t] = *(const bf16x8*)&Bh[br];
      bl[t] = *(const bf16x8*)&Bl[br];
    }
#pragma unroll
    for (int mt = 0; mt < 4; ++mt)
#pragma unroll
      for (int nt = 0; nt < 4; ++nt) {
        acc[mt][nt] = __builtin_amdgcn_mfma_f32_16x16x32_bf16(ah[mt], bh[nt], acc[mt][nt], 0, 0, 0);
        acc[mt][nt] = __builtin_amdgcn_mfma_f32_16x16x32_bf16(al[mt], bh[nt], acc[mt][nt], 0, 0, 0);
        acc[mt][nt] = __builtin_amdgcn_mfma_f32_16x16x32_bf16(ah[mt], bl[nt], acc[mt][nt], 0, 0, 0);
      }
    __syncthreads();
  }

  float* srep = statrep + (size_t)(blockIdx.x & repmask) * REPBLK;

  // ---- epilogue: bias, f32 store (64B-aligned full lines), column stats
#pragma unroll
  for (int nt = 0; nt < 4; ++nt) {
    int c = n0 + wn * 64 + nt * 16 + lm16;
    bool cv = c < NC;
    float bs = cv ? bias[c] : 0.0f;
    float csum = 0.0f, csq = 0.0f;
#pragma unroll
    for (int mt = 0; mt < 4; ++mt) {
      int rbase = m0 + wm * 64 + mt * 16 + quad * 4;
#pragma unroll
      for (int r = 0; r < 4; ++r) {
        int mm = rbase + r;
        if (mm < M && cv) {
          float v = acc[mt][nt][r] + bs;
          Z2[(size_t)mm * NC + c] = v;
          csum += v; csq += v * v;
        }
      }
    }
    csum += __shfl_down(csum, 16); csum += __shfl_down(csum, 32);
    csq  += __shfl_down(csq, 16);  csq  += __shfl_down(csq, 32);
    if (quad == 0 && cv) {
      atomicAdd(&srep[1200 + c], csum);   // sum2
      atomicAdd(&srep[1500 + c], csq);    // sq2
    }
  }
}

// ---------------- host ----------------
// ws layout (floats): [0, NN*EMBD) agg/z2 region
//   wsf = ws + NN*EMBD:
//   wsf[0,600) scale1 | [600,1200) shift1 | [1200,1500) scale2 | [1500,1800) shift2
//   wsf[1800 ...): nrep replicas of REPBLK-float stat accumulators
// nrep = 64 if ws_size allows, else 1.

extern "C" void kernel_launch(void* const* d_in, const int* in_sizes, int n_in,
                              void* d_out, int out_size, void* d_ws, size_t ws_size,
                              hipStream_t stream) {
  const float* x    = (const float*)d_in[0];
  const float* Wb   = (const float*)d_in[1];   // (L, 300, 9)
  const float* eps  = (const float*)d_in[2];   // (L,)
  const float* W1   = (const float*)d_in[3];   // (L, 600, 300)
  const float* b1   = (const float*)d_in[4];   // (L, 600)
  const float* bn1g = (const float*)d_in[5];
  const float* bn1b = (const float*)d_in[6];
  const float* W2   = (const float*)d_in[7];   // (L, 300, 600)
  const float* b2   = (const float*)d_in[8];   // (L, 300)
  const float* bng  = (const float*)d_in[9];
  const float* bnb  = (const float*)d_in[10];
  const int*   ei   = (const int*)d_in[11];    // (2, E)
  const int*   ea   = (const int*)d_in[12];    // (E, 2)

  float* WS  = (float*)d_ws;                   // N x 300 f32 region
  float* OUT = (float*)d_out;                  // N x 300 f32 region (final h)
  float* wsf = (float*)d_ws + (size_t)NN * EMBD;
  float* statrep = wsf + 1800;

  size_t need64 = ((size_t)NN * EMBD + 1800 + (size_t)64 * REPBLK) * sizeof(float);
  int nrep = (ws_size >= need64) ? 64 : 1;
  int repmask = nrep - 1;
  int zn = nrep * REPBLK;

  const int n4 = NN * (EMBD / 4);
  const int eltGrid = (n4 + 255) / 256;

  dim3 g1((NN + TM - 1) / TM, (C1D + TN - 1) / TN);   // 782 x 5
  dim3 g2((NN + TM - 1) / TM, (EMBD + TN - 1) / TN);  // 782 x 3

  preset_ident_k<<<1, 256, 0, stream>>>(wsf);

  for (int l = 0; l < NL; ++l) {
    float* aggp = (l & 1) ? OUT : WS;     // agg -> z2
    float* z1p  = (l & 1) ? WS  : OUT;    // zin region, later z1
    const float* zin = (l == 0) ? x : (const float*)z1p;
    int relu_in = (l > 0) ? 1 : 0;        // zin from layers 0..3 always had relu

    zero_stats_k<<<64, 256, 0, stream>>>(statrep, zn);
    init_agg_k<<<eltGrid, 256, 0, stream>>>(zin, wsf + 1200, wsf + 1500, eps, l, relu_in, aggp);
    edge_scatter_k<<<NE / 4, 256, 0, stream>>>(zin, Wb + (size_t)l * EMBD * 9,
                                               wsf + 1200, wsf + 1500, relu_in, ei, ea, aggp);
    split_agg_k<<<eltGrid, 256, 0, stream>>>((unsigned int*)aggp);
    gemm1_mfma_k<<<g1, 256, 0, stream>>>(
        (const unsigned int*)aggp, W1 + (size_t)l * C1D * EMBD, b1 + (size_t)l * C1D,
        (unsigned short*)z1p, statrep, repmask);
    finalize_k<<<3, 256, 0, stream>>>(statrep, 0, 600, nrep, bn1g + (size_t)l * C1D,
                                      bn1b + (size_t)l * C1D, wsf + 0, wsf + 600, C1D);
    gemm2_mfma_k<<<g2, 256, 0, stream>>>(
        (const unsigned short*)z1p, wsf + 0, wsf + 600,
        W2 + (size_t)l * EMBD * C1D, b2 + (size_t)l * EMBD,
        aggp, statrep, repmask);
    finalize_k<<<2, 256, 0, stream>>>(statrep, 1200, 1500, nrep, bng + (size_t)l * EMBD,
                                      bnb + (size_t)l * EMBD, wsf + 1200, wsf + 1500, EMBD);
  }
  // final output: h = bn2(z2_4), no relu; z2_4 lives in WS (l=4 even)
  bn_apply_k<<<eltGrid, 256, 0, stream>>>(WS, wsf + 1200, wsf + 1500, 0, OUT);
}